// Round 1
// baseline (136.755 us; speedup 1.0000x reference)
//
#include <hip/hip_runtime.h>

#define LEAKY(v) ((v) > 0.0f ? (v) : 0.2f * (v))

// ---- init: deg = 1 (self loop), zero both aggregation buffers ----
__global__ void k_init(float* __restrict__ deg, float* __restrict__ agg1,
                       float* __restrict__ agg2, int n, int aggn) {
    int tid = blockIdx.x * blockDim.x + threadIdx.x;
    if (tid < n) deg[tid] = 1.0f;
    if (tid < aggn) { agg1[tid] = 0.0f; agg2[tid] = 0.0f; }
}

// ---- degree accumulation over edge targets ----
__global__ void k_deg(const int* __restrict__ col, float* __restrict__ deg, int E) {
    int e = blockIdx.x * blockDim.x + threadIdx.x;
    if (e < E) atomicAdd(&deg[col[e]], 1.0f);
}

// ---- xw = x @ W1 (only features 3..5; 0..2 are zeroed) ; fused deg->rsqrt ----
__global__ void k_xw1(const float* __restrict__ x, const float* __restrict__ W1,
                      float* __restrict__ xw, float* __restrict__ deg, int n) {
    int tid = blockIdx.x * blockDim.x + threadIdx.x;
    if (tid >= n * 32) return;
    int j = tid & 31, nn = tid >> 5;
    if (j == 0) deg[nn] = 1.0f / sqrtf(deg[nn]);
    xw[tid] = x[nn * 6 + 3] * W1[96 + j]
            + x[nn * 6 + 4] * W1[128 + j]
            + x[nn * 6 + 5] * W1[160 + j];
}

// ---- scatter: agg[col] += xw[row] * dinv[row]*dinv[col]  (incl. self loops) ----
__global__ void k_scatter(const float* __restrict__ xw, const float* __restrict__ dinv,
                          const int* __restrict__ row, const int* __restrict__ col,
                          float* __restrict__ agg, int E, int n) {
    int tid = blockIdx.x * blockDim.x + threadIdx.x;
    int total = (E + n) * 32;
    if (tid >= total) return;
    int e = tid >> 5, j = tid & 31;
    int r, c; float nrm;
    if (e < E) { r = row[e]; c = col[e]; nrm = dinv[r] * dinv[c]; }
    else       { r = c = e - E; float d = dinv[r]; nrm = d * d; }
    atomicAdd(&agg[c * 32 + j], xw[r * 32 + j] * nrm);
}

// ---- xw2 = leaky(agg1 + b1) @ W2 ----
__global__ void k_xw2(const float* __restrict__ agg1, const float* __restrict__ b1,
                      const float* __restrict__ W2, float* __restrict__ xw, int n) {
    int tid = blockIdx.x * blockDim.x + threadIdx.x;
    if (tid >= n * 32) return;
    int j = tid & 31, nn = tid >> 5;
    const float* a = agg1 + nn * 32;
    float s = 0.0f;
#pragma unroll
    for (int f = 0; f < 32; ++f) {
        float v = a[f] + b1[f];
        v = LEAKY(v);
        s += v * W2[f * 32 + j];
    }
    xw[tid] = s;
}

// ---- conv stage 1: input is agg2 (needs +b2, leaky); CO=3, k=3x2, pool(2,1) ----
__global__ void k_conv1_pool(const float* __restrict__ h2, const float* __restrict__ b2,
                             const float* __restrict__ w, const float* __restrict__ bias,
                             float* __restrict__ out, int Hp, int Wo) {
    int tid = blockIdx.x * blockDim.x + threadIdx.x;
    int total = 3 * Hp * Wo;
    if (tid >= total) return;
    int ow = tid % Wo; int t = tid / Wo; int oh = t % Hp; int co = t / Hp;
    const float* ip = h2 + (2 * oh) * 32 + ow;
    float vals[4][2];
#pragma unroll
    for (int r = 0; r < 4; ++r)
#pragma unroll
        for (int cx = 0; cx < 2; ++cx) {
            float v = ip[r * 32 + cx] + b2[ow + cx];
            vals[r][cx] = LEAKY(v);
        }
    const float* wp = w + co * 6;
    float acc0 = vals[0][0]*wp[0] + vals[0][1]*wp[1] + vals[1][0]*wp[2]
               + vals[1][1]*wp[3] + vals[2][0]*wp[4] + vals[2][1]*wp[5];
    float acc1 = vals[1][0]*wp[0] + vals[1][1]*wp[1] + vals[2][0]*wp[2]
               + vals[2][1]*wp[3] + vals[3][0]*wp[4] + vals[3][1]*wp[5];
    float m = fmaxf(acc0, acc1) + bias[co];
    out[tid] = fmaxf(m, 0.0f);
}

// ---- generic conv (3x2) + relu + pool(2,1); input already post-relu ----
__global__ void k_conv_pool(const float* __restrict__ in, const float* __restrict__ w,
                            const float* __restrict__ bias, float* __restrict__ out,
                            int CI, int CO, int Hin, int Win, int Hp, int Wo) {
    int tid = blockIdx.x * blockDim.x + threadIdx.x;
    int total = CO * Hp * Wo;
    if (tid >= total) return;
    int ow = tid % Wo; int t = tid / Wo; int oh = t % Hp; int co = t / Hp;
    float acc0 = 0.0f, acc1 = 0.0f;
    for (int ci = 0; ci < CI; ++ci) {
        const float* ip = in + (ci * Hin + 2 * oh) * Win + ow;
        const float* wp = w + (co * CI + ci) * 6;
        float r00 = ip[0],         r01 = ip[1];
        float r10 = ip[Win],       r11 = ip[Win + 1];
        float r20 = ip[2 * Win],   r21 = ip[2 * Win + 1];
        float r30 = ip[3 * Win],   r31 = ip[3 * Win + 1];
        acc0 += r00*wp[0] + r01*wp[1] + r10*wp[2] + r11*wp[3] + r20*wp[4] + r21*wp[5];
        acc1 += r10*wp[0] + r11*wp[1] + r20*wp[2] + r21*wp[3] + r30*wp[4] + r31*wp[5];
    }
    float m = fmaxf(acc0, acc1) + bias[co];
    out[tid] = fmaxf(m, 0.0f);
}

// ---- FC: out[o] = dot(v, w[o,:]) + b[o]; one block per output row ----
template <int BLOCK>
__global__ void k_fc(const float* __restrict__ v, const float* __restrict__ w,
                     const float* __restrict__ b, float* __restrict__ out, int IN) {
    int o = blockIdx.x;
    const float* wr = w + (size_t)o * IN;
    float s = 0.0f;
    for (int i = threadIdx.x; i < IN; i += BLOCK) s += v[i] * wr[i];
#pragma unroll
    for (int off = 32; off > 0; off >>= 1) s += __shfl_down(s, off, 64);
    __shared__ float ls[BLOCK / 64];
    int lane = threadIdx.x & 63, wv = threadIdx.x >> 6;
    if (lane == 0) ls[wv] = s;
    __syncthreads();
    if (threadIdx.x == 0) {
        float t = 0.0f;
#pragma unroll
        for (int i = 0; i < BLOCK / 64; ++i) t += ls[i];
        out[o] = t + b[o];
    }
}

extern "C" void kernel_launch(void* const* d_in, const int* in_sizes, int n_in,
                              void* d_out, int out_size, void* d_ws, size_t ws_size,
                              hipStream_t stream) {
    const float* x   = (const float*)d_in[0];
    const int*   ei  = (const int*)d_in[1];
    const float* W1  = (const float*)d_in[2];
    const float* b1  = (const float*)d_in[3];
    const float* W2  = (const float*)d_in[4];
    const float* b2  = (const float*)d_in[5];
    const float* k1  = (const float*)d_in[6];
    const float* kb1 = (const float*)d_in[7];
    const float* k2  = (const float*)d_in[8];
    const float* kb2 = (const float*)d_in[9];
    const float* k3  = (const float*)d_in[10];
    const float* kb3 = (const float*)d_in[11];
    const float* k4  = (const float*)d_in[12];
    const float* kb4 = (const float*)d_in[13];
    const float* fw1 = (const float*)d_in[14];
    const float* fb1 = (const float*)d_in[15];
    const float* fw2 = (const float*)d_in[16];
    const float* fb2 = (const float*)d_in[17];
    const float* fw3 = (const float*)d_in[18];
    const float* fb3 = (const float*)d_in[19];

    int n = in_sizes[0] / 6;       // 1000
    int E = in_sizes[1] / 2;       // 8000
    const int* row = ei;
    const int* col = ei + E;

    float* ws   = (float*)d_ws;
    float* deg  = ws;              // n
    float* xw   = ws + 1024;       // n*32 (reused for both GCN layers)
    float* agg1 = xw + n * 32;     // n*32
    float* agg2 = agg1 + n * 32;   // n*32

    int H1 = (n - 2) / 2,  W1o = 31;   // 499 x 31, CO=3
    int H2 = (H1 - 2) / 2, W2o = 30;   // 248 x 30, CO=6
    int H3 = (H2 - 2) / 2, W3o = 29;   // 123 x 29, CO=3
    int H4 = (H3 - 2) / 2, W4o = 28;   //  60 x 28, CO=1
    float* c1 = agg2 + n * 32;
    float* c2 = c1 + 3 * H1 * W1o;
    float* c3 = c2 + 6 * H2 * W2o;
    float* c4 = c3 + 3 * H3 * W3o;
    float* f1 = c4 + H4 * W4o;
    float* f2 = f1 + 1024;

    const int B = 256;
    int aggn = n * 32;
    int initn = (aggn > n) ? aggn : n;

    k_init<<<(initn + B - 1) / B, B, 0, stream>>>(deg, agg1, agg2, n, aggn);
    k_deg<<<(E + B - 1) / B, B, 0, stream>>>(col, deg, E);
    k_xw1<<<(n * 32 + B - 1) / B, B, 0, stream>>>(x, W1, xw, deg, n);
    int st = (E + n) * 32;
    k_scatter<<<(st + B - 1) / B, B, 0, stream>>>(xw, deg, row, col, agg1, E, n);
    k_xw2<<<(n * 32 + B - 1) / B, B, 0, stream>>>(agg1, b1, W2, xw, n);
    k_scatter<<<(st + B - 1) / B, B, 0, stream>>>(xw, deg, row, col, agg2, E, n);

    k_conv1_pool<<<(3 * H1 * W1o + B - 1) / B, B, 0, stream>>>(agg2, b2, k1, kb1, c1, H1, W1o);
    k_conv_pool<<<(6 * H2 * W2o + B - 1) / B, B, 0, stream>>>(c1, k2, kb2, c2, 3, 6, H1, W1o, H2, W2o);
    k_conv_pool<<<(3 * H3 * W3o + B - 1) / B, B, 0, stream>>>(c2, k3, kb3, c3, 6, 3, H2, W2o, H3, W3o);
    k_conv_pool<<<(1 * H4 * W4o + B - 1) / B, B, 0, stream>>>(c3, k4, kb4, c4, 3, 1, H3, W3o, H4, W4o);

    int IN1 = H4 * W4o;  // 1680
    k_fc<256><<<1024, 256, 0, stream>>>(c4, fw1, fb1, f1, IN1);
    k_fc<256><<<1024, 256, 0, stream>>>(f1, fw2, fb2, f2, 1024);
    k_fc<256><<<64, 256, 0, stream>>>(f2, fw3, fb3, (float*)d_out, 1024);
}